// Round 15
// baseline (371.177 us; speedup 1.0000x reference)
//
#include <hip/hip_runtime.h>

// MoE router: logits = hs @ W^T + b ; probs = softmax ; top-2.
// d_out (float32, concatenated): [0,2T) indices-as-float, [2T,4T) top-2 probs,
// [4T,12T) router_logits.  T=16384 tokens, H=4096, E=8.
//
// Strategy: HBM-bound (268 MB hidden read once; floor ~43us @6.3TB/s).
// Latency-hide via global_load_lds DMA double-buffer: per block, stage
// 16 tokens x 512-float k-tiles (32 KB) into LDS; DMA queue depth (not
// VGPRs) carries the in-flight bytes. W (128 KB) stays L2-resident,
// read directly per-iteration.

constexpr int E    = 8;
constexpr int H    = 4096;
constexpr int H4   = H / 4;        // 1024 float4 per row
constexpr int KT   = 512;          // floats per token per tile
constexpr int KT4  = KT / 4;       // 128 float4
constexpr int NT   = H / KT;       // 8 tiles
constexpr int TPW  = 4;            // tokens per wave
constexpr int WPB  = 4;            // waves per block
constexpr int TPB  = TPW * WPB;    // 16 tokens per block

__global__ __launch_bounds__(256, 2)
void router_kernel(const float* __restrict__ hs,
                   const float* __restrict__ Wm,
                   const float* __restrict__ bias,
                   float* __restrict__ out,
                   int tokens) {
  __shared__ float lds[2][TPB][KT];          // 2 x 32 KB

  const int lane = threadIdx.x & 63;
  const int wv   = threadIdx.x >> 6;
  const int tok0 = blockIdx.x * TPB + wv * TPW;

  const float4* __restrict__ hs4 = reinterpret_cast<const float4*>(hs);
  const float4* __restrict__ W4  = reinterpret_cast<const float4*>(Wm);

  // Clamped token ids (tokens=16384 divides evenly; clamp is safety only).
  int tk[TPW];
#pragma unroll
  for (int t = 0; t < TPW; ++t) {
    int x = tok0 + t;
    tk[t] = (x < tokens) ? x : (tokens - 1);
  }

  // Stage tile `tile` for this wave's 4 tokens into lds[buf].
  // LDS dest is wave-uniform; HW adds lane*16. Global src is per-lane.
  auto stage = [&](int buf, int tile) {
#pragma unroll
    for (int t = 0; t < TPW; ++t) {
#pragma unroll
      for (int half = 0; half < 2; ++half) {
        const float4* src = hs4 + (size_t)tk[t] * H4 + tile * KT4 + half * 64 + lane;
        float* dst = &lds[buf][wv * TPW + t][half * 256];
        __builtin_amdgcn_global_load_lds(
            (const __attribute__((address_space(1))) void*)src,
            (__attribute__((address_space(3))) void*)dst, 16, 0, 0);
      }
    }
  };

  float acc[TPW][E];
#pragma unroll
  for (int t = 0; t < TPW; ++t)
#pragma unroll
    for (int e = 0; e < E; ++e) acc[t][e] = 0.f;

  stage(0, 0);
  __syncthreads();                 // drains vmcnt(0): tile 0 landed

  int buf = 0;
  for (int tile = 0; tile < NT; ++tile) {
    if (tile + 1 < NT) stage(buf ^ 1, tile + 1);   // DMA in flight over compute

    const float4* lw = reinterpret_cast<const float4*>(&lds[buf][wv * TPW][0]);
#pragma unroll
    for (int it = 0; it < KT4 / 64; ++it) {        // 2 iterations
      const int kk = it * 64 + lane;               // float4 idx within tile
      const int kg = tile * KT4 + kk;              // global float4 idx
      float4 h[TPW];
#pragma unroll
      for (int t = 0; t < TPW; ++t) h[t] = lw[t * KT4 + kk];
#pragma unroll
      for (int e = 0; e < E; ++e) {
        const float4 w = W4[(size_t)e * H4 + kg];
#pragma unroll
        for (int t = 0; t < TPW; ++t)
          acc[t][e] += h[t].x * w.x + h[t].y * w.y + h[t].z * w.z + h[t].w * w.w;
      }
    }
    __syncthreads();               // all reads of buf done + next tile landed
    buf ^= 1;
  }

  // Butterfly reduce the 32 partials across the wave.
#pragma unroll
  for (int off = 32; off >= 1; off >>= 1)
#pragma unroll
    for (int t = 0; t < TPW; ++t)
#pragma unroll
      for (int e = 0; e < E; ++e)
        acc[t][e] += __shfl_xor(acc[t][e], off, 64);

  // Lanes 0..3 finish one token each: bias + softmax + top-2 + stores.
  if (lane < TPW) {
    const int t   = lane;
    const int tok = tok0 + t;
    if (tok < tokens) {
      float lg[E];
      float m = -3.4e38f;
#pragma unroll
      for (int e = 0; e < E; ++e) {
        lg[e] = acc[t][e] + bias[e];
        m = fmaxf(m, lg[e]);
      }
      float p[E];
      float s = 0.f;
#pragma unroll
      for (int e = 0; e < E; ++e) { p[e] = expf(lg[e] - m); s += p[e]; }
      const float inv = 1.f / s;
#pragma unroll
      for (int e = 0; e < E; ++e) p[e] *= inv;

      // top-2; strict '>' keeps lowest index on ties (jax.lax.top_k semantics)
      int i0 = 0; float p0 = p[0];
#pragma unroll
      for (int e = 1; e < E; ++e) if (p[e] > p0) { p0 = p[e]; i0 = e; }
      int i1 = (i0 == 0) ? 1 : 0; float p1 = p[i1];
#pragma unroll
      for (int e = 0; e < E; ++e)
        if (e != i0 && p[e] > p1) { p1 = p[e]; i1 = e; }

      out[2 * tok]     = (float)i0;
      out[2 * tok + 1] = (float)i1;
      float* ow = out + 2 * (size_t)tokens;
      ow[2 * tok]     = p0;
      ow[2 * tok + 1] = p1;
      float4* o4 = reinterpret_cast<float4*>(out + 4 * (size_t)tokens + (size_t)tok * E);
      o4[0] = make_float4(lg[0], lg[1], lg[2], lg[3]);
      o4[1] = make_float4(lg[4], lg[5], lg[6], lg[7]);
    }
  }
}

extern "C" void kernel_launch(void* const* d_in, const int* in_sizes, int n_in,
                              void* d_out, int out_size, void* d_ws, size_t ws_size,
                              hipStream_t stream) {
  const float* hs = (const float*)d_in[0];
  const float* Wm = (const float*)d_in[1];
  const float* b  = (const float*)d_in[2];
  float* out      = (float*)d_out;
  const int tokens = in_sizes[0] / H;            // 16384
  const int blocks = (tokens + TPB - 1) / TPB;   // 1024
  router_kernel<<<blocks, 256, 0, stream>>>(hs, Wm, b, out, tokens);
}